// Round 3
// baseline (4689.106 us; speedup 1.0000x reference)
//
#include <hip/hip_runtime.h>

// ---- problem constants ----
#define T_SEQ 1000
#define NS 128
#define NE 4
#define DIN 132
#define G3 768
#define WGS 512

typedef __attribute__((ext_vector_type(8))) short short8;
typedef __attribute__((ext_vector_type(4))) float floatx4;

// ---- workspace layout (bytes) ----
#define CNT_OFF 0
#define HX_OFF  131072
#define HX_BYTES (32*2*8192)             // per group: 2 slots x 8 frags x 64 lanes x 16B
#define WS_ZERO_BYTES (HX_OFF + HX_BYTES)

#define MFMA16(a,b,c) __builtin_amdgcn_mfma_f32_16x16x32_bf16((a),(b),(c),0,0,0)

__device__ __forceinline__ unsigned short f2bf(float f){
  unsigned u = __float_as_uint(f);
  return (unsigned short)((u + 0x7FFFu + ((u>>16)&1u)) >> 16);   // RNE
}
__device__ __forceinline__ float bf2f(unsigned short b){
  return __uint_as_float(((unsigned)b)<<16);
}
__device__ __forceinline__ unsigned long long ld64a(const void* p){
  return __hip_atomic_load((const unsigned long long*)p, __ATOMIC_RELAXED, __HIP_MEMORY_SCOPE_AGENT);
}
__device__ __forceinline__ void st32a(void* p, unsigned v){
  __hip_atomic_store((unsigned*)p, v, __ATOMIC_RELAXED, __HIP_MEMORY_SCOPE_AGENT);
}

__global__ __launch_bounds__(WGS, 1) void bigru3(
  const float* __restrict__ spike, const float* __restrict__ extin,
  const int* __restrict__ lens,
  const float* __restrict__ WiF, const float* __restrict__ WhF,
  const float* __restrict__ biF, const float* __restrict__ bhF,
  const float* __restrict__ WiB, const float* __restrict__ WhB,
  const float* __restrict__ biB, const float* __restrict__ bhB,
  float* __restrict__ out,
  unsigned* __restrict__ cnt, char* __restrict__ hx)
{
  const int tid = threadIdx.x;
  const int bid = blockIdx.x;
  const int g   = bid >> 2;          // group 0..31 (16 fwd, 16 bwd)
  const int s   = bid & 3;           // column-slice 0..3 (64 h-dims each)
  const int dir = g >> 4;
  const int b_base = (g & 15) << 4;  // 16 examples per group
  const int w  = tid >> 6;           // wave 0..7
  const int l  = tid & 63;
  const int dg = w >> 1;             // dim-group 0..3 (16 dims)
  const int ks = w & 1;              // K-half
  const int col = l & 15;
  const int q   = l >> 4;
  const int jd  = s*64 + dg*16 + col;   // global h-dim 0..255

  const float* Wi  = dir ? WiB : WiF;
  const float* Wh  = dir ? WhB : WhF;
  const float* bi  = dir ? biB : biF;
  const float* bhn = dir ? bhB : bhF;

  __shared__ __align__(16) char  ldsXb[2*5*64*16];   // x A-frags, double-buffered
  __shared__ __align__(16) float ldsC[4][4][16][20]; // K-split partials, padded
  __shared__ int ldsL[16];

  unsigned* cg  = cnt + g*T_SEQ;          // cnt[t] = #ks1-wave signals for step t (target 16)
  char*     hxg = hx + (size_t)g*2*8192;

  if (tid < 16) ldsL[tid] = lens[b_base + tid];
  for (int i = tid; i < 2*320; i += WGS)
    *(floatx4*)(ldsXb + i*16) = floatx4{0.f,0.f,0.f,0.f};
  __syncthreads();

  // ---- persistent B fragments (W = W_hi + W_lo, both bf16) ----
  const int q8 = q*8;
  short8 Bh[4][3][2];   // [h-kg][gate][hi/lo]
  short8 Bx[3][3][2];   // [x-kg][gate][hi/lo]
  #pragma unroll
  for (int hk=0; hk<4; ++hk){
    const int k0 = (ks*4+hk)*32 + q8;
    #pragma unroll
    for (int gt=0; gt<3; ++gt){
      const int c = gt*256 + jd;
      #pragma unroll
      for (int i=0;i<8;++i){
        float wv = Wh[(size_t)(k0+i)*G3 + c];
        unsigned short hb = f2bf(wv);
        Bh[hk][gt][0][i] = (short)hb;
        Bh[hk][gt][1][i] = (short)f2bf(wv - bf2f(hb));
      }
    }
  }
  #pragma unroll
  for (int xk=0; xk<3; ++xk){
    const bool xv = (ks==0) || (xk<2);
    const int kxg = (ks==0) ? xk : (3+xk);
    const int k0 = kxg*32 + q8;
    #pragma unroll
    for (int gt=0; gt<3; ++gt){
      const int c = gt*256 + jd;
      #pragma unroll
      for (int i=0;i<8;++i){
        float wv = (xv && (k0+i) < DIN) ? Wi[(size_t)(k0+i)*G3 + c] : 0.f;
        unsigned short hb = f2bf(wv);
        Bx[xk][gt][0][i] = (short)hb;
        Bx[xk][gt][1][i] = (short)f2bf(wv - bf2f(hb));
      }
    }
  }

  const float bir = bi[jd], biz = bi[256+jd], bin = bi[512+jd], bhv = bhn[jd];
  int   Lr[4];
  float hold[4];
  #pragma unroll
  for (int j=0;j<4;++j){ Lr[j] = ldsL[q*4+j]; hold[j] = 0.f; }

  // x staging helpers: pack m (row = m/33, k0 = (m%33)*4)
  auto xload = [&](int m, int tt)->float4{
    const int row = m/33, pk = m - row*33, k0 = pk*4;
    const int L = ldsL[row];
    int tp = dir ? (L-1-tt) : tt;
    if (tp < 0) tp += T_SEQ;
    const size_t xb = (size_t)(b_base+row)*T_SEQ + tp;
    if (k0 < NS) return *(const float4*)(spike + xb*NS + k0);
    return *(const float4*)(extin + xb*NE);        // k0 == 128 -> externals
  };
  auto xstore = [&](int m, float4 v, int buf){
    const int row = m/33, pk = m - row*33, k0 = pk*4;
    const int kg = k0>>5, sub = (k0>>3)&3, ii = k0&7;
    const int off = buf*5120 + ((kg*64 + row + 16*sub)*8 + ii)*2;
    unsigned lo = (unsigned)f2bf(v.x) | (((unsigned)f2bf(v.y))<<16);
    unsigned hi = (unsigned)f2bf(v.z) | (((unsigned)f2bf(v.w))<<16);
    *(unsigned*)(ldsXb + off)     = lo;
    *(unsigned*)(ldsXb + off + 4) = hi;
  };

  // prologue: stage x(0) into buffer 0
  {
    float4 a = xload(tid, 0);  xstore(tid, a, 0);
    if (tid < 16){ float4 b = xload(tid+512, 0); xstore(tid+512, b, 0); }
  }
  __syncthreads();

  const int r0 = dg*64 + l;   // ks0 staging pack base

  for (int t=0; t<T_SEQ; ++t){
    const int cur = t & 1, nxt = cur ^ 1;

    // phase A: issue x(t+1) loads (ks0 threads), then x-part MFMAs (all waves)
    float4 sx0, sx1, sx2;
    if (ks==0 && t < T_SEQ-1){
      sx0 = xload(r0, t+1);
      sx1 = xload(r0+256, t+1);
      if (r0 < 16) sx2 = xload(r0+512, t+1);
    }

    floatx4 aR={0.f,0.f,0.f,0.f}, aZ={0.f,0.f,0.f,0.f}, aNH={0.f,0.f,0.f,0.f}, aNX={0.f,0.f,0.f,0.f};
    if (ks==0){
      #pragma unroll
      for (int xk=0; xk<3; ++xk){
        const short8 a = *(const short8*)(ldsXb + (cur*320 + xk*64 + l)*16);
        aR  = MFMA16(a, Bx[xk][0][0], aR ); aZ  = MFMA16(a, Bx[xk][1][0], aZ ); aNX = MFMA16(a, Bx[xk][2][0], aNX);
        aR  = MFMA16(a, Bx[xk][0][1], aR ); aZ  = MFMA16(a, Bx[xk][1][1], aZ ); aNX = MFMA16(a, Bx[xk][2][1], aNX);
      }
    } else {
      #pragma unroll
      for (int xk=0; xk<2; ++xk){
        const short8 a = *(const short8*)(ldsXb + (cur*320 + (3+xk)*64 + l)*16);
        aR  = MFMA16(a, Bx[xk][0][0], aR ); aZ  = MFMA16(a, Bx[xk][1][0], aZ ); aNX = MFMA16(a, Bx[xk][2][0], aNX);
        aR  = MFMA16(a, Bx[xk][0][1], aR ); aZ  = MFMA16(a, Bx[xk][1][1], aZ ); aNX = MFMA16(a, Bx[xk][2][1], aNX);
      }
    }

    // phase B: every wave polls the group counter itself (no broadcast barrier)
    if (t > 0){
      const unsigned* cp = &cg[t-1];
      while (__hip_atomic_load(cp, __ATOMIC_RELAXED, __HIP_MEMORY_SCOPE_AGENT) < 16u)
        __builtin_amdgcn_s_sleep(1);
      asm volatile("" ::: "memory");
    }

    // phase C: each wave loads its own 4 h(t-1) A-frags straight from LLC
    short8 hf[4];
    {
      const char* hsrc = hxg + nxt*8192;
      #pragma unroll
      for (int hk=0; hk<4; ++hk){
        const char* p = hsrc + (((ks*4+hk)*64 + l)*16);
        union { unsigned long long qq[2]; short8 v; } u;
        u.qq[0] = ld64a(p); u.qq[1] = ld64a(p+8);
        hf[hk] = u.v;
      }
    }

    // phase D: h-part MFMAs
    #pragma unroll
    for (int hk=0; hk<4; ++hk){
      aR  = MFMA16(hf[hk], Bh[hk][0][0], aR ); aZ  = MFMA16(hf[hk], Bh[hk][1][0], aZ ); aNH = MFMA16(hf[hk], Bh[hk][2][0], aNH);
      aR  = MFMA16(hf[hk], Bh[hk][0][1], aR ); aZ  = MFMA16(hf[hk], Bh[hk][1][1], aZ ); aNH = MFMA16(hf[hk], Bh[hk][2][1], aNH);
    }

    if (ks==0){
      *(floatx4*)&ldsC[dg][0][col][q*4] = aR;
      *(floatx4*)&ldsC[dg][1][col][q*4] = aZ;
      *(floatx4*)&ldsC[dg][2][col][q*4] = aNH;
      *(floatx4*)&ldsC[dg][3][col][q*4] = aNX;
    }
    __syncthreads();   // barrier1

    if (ks==1){
      aR  += *(const floatx4*)&ldsC[dg][0][col][q*4];
      aZ  += *(const floatx4*)&ldsC[dg][1][col][q*4];
      aNH += *(const floatx4*)&ldsC[dg][2][col][q*4];
      aNX += *(const floatx4*)&ldsC[dg][3][col][q*4];
      unsigned dwj[4];
      #pragma unroll
      for (int j=0;j<4;++j){
        const int rj = q*4 + j;
        const float gr = aR[j] + bir;
        const float gz = aZ[j] + biz;
        const float r = __fdividef(1.f, 1.f + __expf(-gr));
        const float z = __fdividef(1.f, 1.f + __expf(-gz));
        float pn = aNX[j] + bin + r*(aNH[j] + bhv);
        pn = fminf(fmaxf(pn, -20.f), 20.f);
        const float e2 = __expf(-2.f*pn);
        const float n  = __fdividef(1.f - e2, 1.f + e2);
        const float hn  = (1.f - z)*n + z*hold[j];
        const float hnx = (t < Lr[j]) ? hn : hold[j];   // keep state on padding
        hold[j] = hnx;
        int tp = dir ? (Lr[j]-1-t) : t;
        if (tp < 0) tp += T_SEQ;
        out[((size_t)(b_base+rj)*T_SEQ + tp)*512 + dir*256 + jd] = hn;  // new_h always
        // pack (even dim, odd dim) bf16 pair across lane l / l^1
        unsigned bf = f2bf(hnx);
        unsigned ot = (unsigned)__shfl_xor((int)bf, 1);
        dwj[j] = (l & 1) ? 0u : (bf | (ot << 16));
      }
      if (t < T_SEQ-1){
        if ((l & 1) == 0){
          const int kg = jd >> 5, d5 = jd & 31;
          char* dst = hxg + cur*8192 + ((kg*64 + 16*(d5>>3))*16 + (d5&7)*2);
          #pragma unroll
          for (int j=0;j<4;++j)
            st32a(dst + (q*4+j)*16, dwj[j]);
        }
        asm volatile("s_waitcnt vmcnt(0)" ::: "memory");
        if (l == 0)
          __hip_atomic_fetch_add(&cg[t], 1u, __ATOMIC_RELAXED, __HIP_MEMORY_SCOPE_AGENT);
      }
    } else {
      if (t < T_SEQ-1){
        xstore(r0, sx0, nxt);
        xstore(r0+256, sx1, nxt);
        if (r0 < 16) xstore(r0+512, sx2, nxt);
      }
    }
    __syncthreads();   // barrier2
  }
}

extern "C" void kernel_launch(void* const* d_in, const int* in_sizes, int n_in,
                              void* d_out, int out_size, void* d_ws, size_t ws_size,
                              hipStream_t stream) {
  (void)in_sizes; (void)n_in; (void)out_size; (void)ws_size;
  const float* spike = (const float*)d_in[0];
  const float* extin = (const float*)d_in[1];
  const int*   lens  = (const int*)  d_in[2];
  const float* WiF   = (const float*)d_in[3];
  const float* WhF   = (const float*)d_in[4];
  const float* biF   = (const float*)d_in[5];
  const float* bhF   = (const float*)d_in[6];
  const float* WiB   = (const float*)d_in[7];
  const float* WhB   = (const float*)d_in[8];
  const float* biB   = (const float*)d_in[9];
  const float* bhB   = (const float*)d_in[10];
  float* out = (float*)d_out;
  char* ws = (char*)d_ws;
  unsigned* cnt = (unsigned*)(ws + CNT_OFF);
  char*     hx  = ws + HX_OFF;

  // zero counters + both frag slots (slot 1 must read as h=0 at t=0; also
  // required between graph replays since the kernel leaves state behind)
  hipMemsetAsync(ws, 0, WS_ZERO_BYTES, stream);
  bigru3<<<dim3(128), dim3(WGS), 0, stream>>>(
      spike, extin, lens, WiF, WhF, biF, bhF, WiB, WhB, biB, bhB, out, cnt, hx);
}